// Round 4
// baseline (3410.041 us; speedup 1.0000x reference)
//
#include <hip/hip_runtime.h>

typedef short short8 __attribute__((ext_vector_type(8)));
typedef float floatx4 __attribute__((ext_vector_type(4)));
typedef unsigned short u16;
typedef unsigned u32;
typedef unsigned long long u64;
typedef u32 u32x4 __attribute__((ext_vector_type(4)));

#define MFMA16 __builtin_amdgcn_mfma_f32_16x16x32_bf16

#define B_  64
#define T_  512
#define I_  256
#define H_  1024
#define XS_STRIDE 272    // u16; 544B = 8 banks mod 32 -> 2-way max on A-reads
#define HS_STRIDE 1040   // u16; 2080B = 8 banks mod 32
#define FAST_TRIES 24    // sc0 re-sweeps before sticky fallback to agent scope

// round-to-nearest-even fp32 -> bf16 (as u16)
__device__ __forceinline__ u16 rne_bf(float f) {
    union { float f; u32 i; } v; v.f = f;
    return (u16)((v.i + 0x7fffu + ((v.i >> 16) & 1u)) >> 16);
}
// split fp32 into bf16 hi + bf16 lo (hi RNE, lo = RNE(f - hi)); |f-hi-lo| <= 2^-16 |f|
__device__ __forceinline__ void split_bf(float f, u16& hi, u16& lo) {
    u16 h = rne_bf(f);
    union { u32 i; float f; } hf; hf.i = ((u32)h) << 16;
    hi = h;
    lo = rne_bf(f - hf.f);
}
__device__ __forceinline__ void split4(float4 v, u64& hi64, u64& lo64) {
    u16 h0,l0,h1,l1,h2,l2,h3,l3;
    split_bf(v.x,h0,l0); split_bf(v.y,h1,l1);
    split_bf(v.z,h2,l2); split_bf(v.w,h3,l3);
    hi64 = (u64)h0 | ((u64)h1 << 16) | ((u64)h2 << 32) | ((u64)h3 << 48);
    lo64 = (u64)l0 | ((u64)l1 << 16) | ((u64)l2 << 32) | ((u64)l3 << 48);
}

// sc0-only load: bypass L1, read the (XCD-local, coherent) L2. This is the
// "XCD scope" HIP doesn't expose. 16B = two packed h elements.
__device__ __forceinline__ u32x4 ld_sc0_x4(const u64* p) {
    u32x4 r;
    asm volatile("global_load_dwordx4 %0, %1, off sc0" : "=v"(r) : "v"(p));
    return r;
}
// Drain inline-asm loads; sched_barrier stops hipcc hoisting the dependent
// tag-checks above the waitcnt (rule: compiler ignores asm vmcnt for reg ops).
__device__ __forceinline__ void vm_drain() {
    asm volatile("s_waitcnt vmcnt(0)" ::: "memory");
    __builtin_amdgcn_sched_barrier(0);
}

// grid = 256 blocks: blockIdx = cb*16 + g
//   g  (0..15): batch group, batches 4g..4g+3
//   cb (0..15): column block, cols 64cb..64cb+63
// The 16 peers of a group are blockIdx ≡ g (mod 8) -> SAME XCD under the
// empirical round-robin dispatch -> they share one coherent L2.
//
// h exchange: tagged u64 values (tag=step)<<48 | lo_bf16<<16 | hi_bf16.
// Producers publish each value TWICE: plain store (lands in own L2 ->
// fast path for same-XCD peers via sc0 loads, ~200cy) and sc1 agent store
// (lands at MALL -> correctness fallback if dispatch mapping ever differs).
// Consumers poll sc0 for up to FAST_TRIES sweeps, then stick to agent loads.
// Tag mismatch just re-polls, so a stale L2 line can never deadlock.
__global__ __launch_bounds__(256, 1) void leaky_rnn(
    const float* __restrict__ x, const float* __restrict__ eps,
    const float* __restrict__ in_w, const float* __restrict__ in_b,
    const float* __restrict__ W, const float* __restrict__ taus,
    float* __restrict__ out, u64* __restrict__ hbf, unsigned* __restrict__ cnt)
{
    __shared__ float Wl[128 * 68];           // init-only W staging
    __shared__ u16 xs_hi[4 * XS_STRIDE];
    __shared__ u16 xs_lo[4 * XS_STRIDE];
    __shared__ u16 hs_hi[4 * HS_STRIDE];
    __shared__ u16 hs_lo[4 * HS_STRIDE];

    const int tid  = threadIdx.x;
    const int wave = tid >> 6;
    const int lane = tid & 63;
    const int n    = lane & 15;
    const int quad = lane >> 4;
    const int g    = blockIdx.x & 15;
    const int cb   = blockIdx.x >> 4;
    const int jme  = cb * 64 + wave * 16 + n;   // my output column

    // ---- init: W column-slice -> split-bf16 register B-fragments ----
    // FULL unroll: runtime-indexed ext_vector arrays go to scratch (17 GB lesson).
    short8 whi[32], wlo[32];
    #pragma unroll
    for (int ph = 0; ph < 8; ++ph) {            // 8 phases x 128 rows
        #pragma unroll
        for (int ii = 0; ii < 8; ++ii) {        // stage 128x64 fp32 tile
            int f4i = ii * 256 + tid;           // 2048 float4
            int row = f4i >> 4, c4 = (f4i & 15) * 4;
            *(float4*)(Wl + row * 68 + c4) =
                *(const float4*)(W + (size_t)(ph * 128 + row) * H_ + cb * 64 + c4);
        }
        __syncthreads();
        #pragma unroll
        for (int ckl = 0; ckl < 4; ++ckl) {     // K-chunks of 32 within phase
            short8 fh, fl;
            #pragma unroll
            for (int i = 0; i < 8; ++i) {
                float v = Wl[(ckl * 32 + quad * 8 + i) * 68 + wave * 16 + n];
                u16 h, l; split_bf(v, h, l);
                fh[i] = (short)h; fl[i] = (short)l;
            }
            whi[ph * 4 + ckl] = fh;
            wlo[ph * 4 + ckl] = fl;
        }
        __syncthreads();
    }

    // in_w fragments: B[k][col] = in_w[col][k] -> 8 consecutive fp32 per chunk
    short8 iwhi[8], iwlo[8];
    #pragma unroll
    for (int ck = 0; ck < 8; ++ck) {
        float4 a = *(const float4*)(in_w + (size_t)jme * I_ + ck * 32 + quad * 8);
        float4 b = *(const float4*)(in_w + (size_t)jme * I_ + ck * 32 + quad * 8 + 4);
        short8 fh, fl;
        float vv[8] = {a.x, a.y, a.z, a.w, b.x, b.y, b.z, b.w};
        #pragma unroll
        for (int i = 0; i < 8; ++i) {
            u16 h, l; split_bf(vv[i], h, l);
            fh[i] = (short)h; fl[i] = (short)l;
        }
        iwhi[ck] = fh; iwlo[ck] = fl;
    }

    // per-column params (alpha time-invariant)
    float tv = taus[jme];
    float sg = 1.0f / (1.0f + __expf(-tv));
    float al = 10.0f / (sg * 90.0f + 10.0f);   // DT / (sigmoid(taus)*range + min)
    float om = 1.0f - al;
    float bj = in_b[jme];
    float hm[4] = {0.f, 0.f, 0.f, 0.f};        // fp32 master h (quad-0 lanes)

    // ---- prologue: prefetch x(0), eps(0) into registers ----
    float4 xv;
    float epr[4] = {0.f, 0.f, 0.f, 0.f};
    {
        int b = tid >> 6, c = (tid & 63) * 4;
        xv = *(const float4*)(x + ((size_t)(g * 4 + b) * T_ + 0) * I_ + c);
    }
    if (quad == 0) {
        #pragma unroll
        for (int r = 0; r < 4; ++r)
            epr[r] = eps[((size_t)(g * 4 + r) * T_ + 0) * H_ + jme];
    }

    bool slow = false;   // sticky: set if sc0 fast path can't see peers (bad mapping)

    #pragma unroll 1
    for (int t = 0; t < T_; ++t) {
        // ---- stage x_t (already in registers) -> split-bf16 LDS ----
        {
            int b = tid >> 6, c = (tid & 63) * 4;    // 256 float4 = [4][256]
            u64 hi64, lo64; split4(xv, hi64, lo64);
            *(u64*)(xs_hi + b * XS_STRIDE + c) = hi64;
            *(u64*)(xs_lo + b * XS_STRIDE + c) = lo64;
        }
        __syncthreads();                                        // S0: xs ready

        // ---- issue initial h_t sweep: 8 x dwordx4 (2 packed elems each) ----
        u64* src8 = hbf + ((size_t)(t & 1) * 16 + g) * 4096;
        u32x4 hv[8];
        if (!slow) {
            #pragma unroll
            for (int ii = 0; ii < 8; ++ii)
                hv[ii] = ld_sc0_x4(src8 + ii * 512 + tid * 2);
        } else {
            #pragma unroll
            for (int ii = 0; ii < 8; ++ii) {
                u64 e0 = __hip_atomic_load(src8 + ii * 512 + tid * 2,
                                           __ATOMIC_RELAXED, __HIP_MEMORY_SCOPE_AGENT);
                u64 e1 = __hip_atomic_load(src8 + ii * 512 + tid * 2 + 1,
                                           __ATOMIC_RELAXED, __HIP_MEMORY_SCOPE_AGENT);
                hv[ii].x = (u32)e0; hv[ii].y = (u32)(e0 >> 32);
                hv[ii].z = (u32)e1; hv[ii].w = (u32)(e1 >> 32);
            }
        }

        // ---- x @ in_w^T while the sweep is in flight (24 MFMAs) ----
        floatx4 acc[8];
        #pragma unroll
        for (int a8 = 0; a8 < 8; ++a8) { floatx4 z = {0.f,0.f,0.f,0.f}; acc[a8] = z; }
        {
            const u16* xh = xs_hi + (n & 3) * XS_STRIDE + quad * 8;
            const u16* xl = xs_lo + (n & 3) * XS_STRIDE + quad * 8;
            #pragma unroll
            for (int ck = 0; ck < 8; ++ck) {
                short8 ah  = *(const short8*)(xh + ck * 32);
                short8 al8 = *(const short8*)(xl + ck * 32);
                acc[(3*ck+0)&7] = MFMA16(ah,  iwhi[ck], acc[(3*ck+0)&7], 0, 0, 0);
                acc[(3*ck+1)&7] = MFMA16(ah,  iwlo[ck], acc[(3*ck+1)&7], 0, 0, 0);
                acc[(3*ck+2)&7] = MFMA16(al8, iwhi[ck], acc[(3*ck+2)&7], 0, 0, 0);
            }
        }

        vm_drain();                         // asm loads valid past this point

        // ---- tag verify + re-poll: tag lives in bits[31:16] of .y/.w ----
        const u32 tt = (u32)t;
        u32 pend = 0;
        #pragma unroll
        for (int ii = 0; ii < 8; ++ii)
            if ((hv[ii].y >> 16) != tt || (hv[ii].w >> 16) != tt) pend |= 1u << ii;

        if (!slow && pend) {
            for (int it = 0; it < FAST_TRIES && pend; ++it) {
                #pragma unroll
                for (int ii = 0; ii < 8; ++ii)
                    if (pend & (1u << ii))
                        hv[ii] = ld_sc0_x4(src8 + ii * 512 + tid * 2);
                vm_drain();
                #pragma unroll
                for (int ii = 0; ii < 8; ++ii)
                    if ((hv[ii].y >> 16) == tt && (hv[ii].w >> 16) == tt)
                        pend &= ~(1u << ii);
            }
            if (pend) slow = true;          // sc0 can't see a peer -> cross-XCD
        }
        while (pend) {                      // correctness fallback: MALL copy
            #pragma unroll
            for (int ii = 0; ii < 8; ++ii)
                if (pend & (1u << ii)) {
                    u64 e0 = __hip_atomic_load(src8 + ii * 512 + tid * 2,
                                               __ATOMIC_RELAXED, __HIP_MEMORY_SCOPE_AGENT);
                    u64 e1 = __hip_atomic_load(src8 + ii * 512 + tid * 2 + 1,
                                               __ATOMIC_RELAXED, __HIP_MEMORY_SCOPE_AGENT);
                    hv[ii].x = (u32)e0; hv[ii].y = (u32)(e0 >> 32);
                    hv[ii].z = (u32)e1; hv[ii].w = (u32)(e1 >> 32);
                }
            #pragma unroll
            for (int ii = 0; ii < 8; ++ii)
                if ((hv[ii].y >> 16) == tt && (hv[ii].w >> 16) == tt)
                    pend &= ~(1u << ii);
        }

        // ---- unpack pre-split bf16 pairs -> LDS (u32 writes, sequential) ----
        #pragma unroll
        for (int ii = 0; ii < 8; ++ii) {
            int e0 = ii * 512 + tid * 2;           // even
            int b = e0 >> 10, c = e0 & 1023;
            *(u32*)(hs_hi + b * HS_STRIDE + c) = (hv[ii].x & 0xffffu) | (hv[ii].z << 16);
            *(u32*)(hs_lo + b * HS_STRIDE + c) = (hv[ii].x >> 16) | (hv[ii].z & 0xffff0000u);
        }
        __syncthreads();                                        // S2: hs ready

        // ---- prefetch x/eps for t+1 (latency hides under hW MFMAs) ----
        float4 xvn;
        float eprn[4] = {0.f, 0.f, 0.f, 0.f};
        {
            int tn = (t < T_ - 1) ? t + 1 : t;
            int b = tid >> 6, c = (tid & 63) * 4;
            xvn = *(const float4*)(x + ((size_t)(g * 4 + b) * T_ + tn) * I_ + c);
            if (quad == 0) {
                #pragma unroll
                for (int r = 0; r < 4; ++r)
                    eprn[r] = eps[((size_t)(g * 4 + r) * T_ + tn) * H_ + jme];
            }
        }

        // ---- h @ W: 32 K-chunks x 3 split terms = 96 MFMAs ----
        {
            const u16* hh = hs_hi + (n & 3) * HS_STRIDE + quad * 8;
            const u16* hl = hs_lo + (n & 3) * HS_STRIDE + quad * 8;
            #pragma unroll
            for (int ck = 0; ck < 32; ++ck) {
                short8 ah  = *(const short8*)(hh + ck * 32);
                short8 al8 = *(const short8*)(hl + ck * 32);
                acc[(3*ck+0)&7] = MFMA16(ah,  whi[ck], acc[(3*ck+0)&7], 0, 0, 0);
                acc[(3*ck+1)&7] = MFMA16(ah,  wlo[ck], acc[(3*ck+1)&7], 0, 0, 0);
                acc[(3*ck+2)&7] = MFMA16(al8, whi[ck], acc[(3*ck+2)&7], 0, 0, 0);
            }
        }

        // ---- epilogue: C/D row = quad*4+reg -> quad 0 holds batches 0..3 ----
        if (quad == 0) {
            u64* dst8 = hbf + ((size_t)((t + 1) & 1) * 16 + g) * 4096;
            #pragma unroll
            for (int r = 0; r < 4; ++r) {
                float pre = acc[0][r] + acc[1][r] + acc[2][r] + acc[3][r]
                          + acc[4][r] + acc[5][r] + acc[6][r] + acc[7][r]
                          + bj + 0.1f * epr[r];
                float ex = __expf(2.0f * pre);                 // tanh = 1 - 2/(e^2x+1)
                float th = 1.0f - 2.0f / (ex + 1.0f);
                hm[r] = om * hm[r] + al * th;
                out[((size_t)(g * 4 + r) * T_ + t) * H_ + jme] = hm[r];
                u16 phh, pll; split_bf(hm[r], phh, pll);
                u64 pk = (u64)phh | ((u64)pll << 16) | ((u64)(u32)(t + 1) << 48);
                u64* p = dst8 + r * 1024 + jme;
                // fast path: plain store -> own (XCD-shared) L2, write-through L1
                __hip_atomic_store(p, pk, __ATOMIC_RELAXED, __HIP_MEMORY_SCOPE_WORKGROUP);
                // fallback: sc1 store -> MALL (for cross-XCD consumers)
                __hip_atomic_store(p, pk, __ATOMIC_RELAXED, __HIP_MEMORY_SCOPE_AGENT);
            }
        }

        // roll prefetched registers
        xv = xvn;
        #pragma unroll
        for (int r = 0; r < 4; ++r) epr[r] = eprn[r];
        // No end-of-step barrier: a wave writing xs at t+1 passed S2(t), which
        // all waves reached only after their xs reads; hs writes at t+1 come
        // after S0(t+1), which requires all waves past t's hW reads.
    }
}

extern "C" void kernel_launch(void* const* d_in, const int* in_sizes, int n_in,
                              void* d_out, int out_size, void* d_ws, size_t ws_size,
                              hipStream_t stream) {
    const float* x    = (const float*)d_in[0];
    const float* eps  = (const float*)d_in[1];
    const float* in_w = (const float*)d_in[2];
    const float* in_b = (const float*)d_in[3];
    const float* W    = (const float*)d_in[4];
    const float* taus = (const float*)d_in[5];
    float* out = (float*)d_out;

    unsigned* cnt = (unsigned*)d_ws;                   // unused (kept for layout)
    u64* hbf = (u64*)((char*)d_ws + 4096);             // [parity][16 groups][4096] u64

    // zero BOTH parity slots: tag 0 == step 0 (h0 = 0); stale tags from a
    // previous dispatch must never alias a live step tag.
    hipMemsetAsync(d_ws, 0, 4096 + 2 * 16 * 4096 * sizeof(u64), stream);

    leaky_rnn<<<dim3(256), dim3(256), 0, stream>>>(x, eps, in_w, in_b, W, taus,
                                                   out, hbf, cnt);
}

// Round 5
// 2312.909 us; speedup vs baseline: 1.4744x; 1.4744x over previous
//
#include <hip/hip_runtime.h>

typedef short short8 __attribute__((ext_vector_type(8)));
typedef float floatx4 __attribute__((ext_vector_type(4)));
typedef unsigned short u16;
typedef unsigned u32;
typedef unsigned long long u64;

#define MFMA16 __builtin_amdgcn_mfma_f32_16x16x32_bf16

#define B_  64
#define T_  512
#define I_  256
#define H_  1024
#define XS_STRIDE 272    // u16; 544B = 8 banks mod 32 -> 2-way max on A-reads
#define HS_STRIDE 1040   // u16; 2080B = 8 banks mod 32
#define XS_HALF   (4 * XS_STRIDE)   // one parity's xs tile (u16 count)

// round-to-nearest-even fp32 -> bf16 (as u16)
__device__ __forceinline__ u16 rne_bf(float f) {
    union { float f; u32 i; } v; v.f = f;
    return (u16)((v.i + 0x7fffu + ((v.i >> 16) & 1u)) >> 16);
}
// split fp32 into bf16 hi + bf16 lo (hi RNE, lo = RNE(f - hi)); |f-hi-lo| <= 2^-16 |f|
__device__ __forceinline__ void split_bf(float f, u16& hi, u16& lo) {
    u16 h = rne_bf(f);
    union { u32 i; float f; } hf; hf.i = ((u32)h) << 16;
    hi = h;
    lo = rne_bf(f - hf.f);
}
__device__ __forceinline__ void split4(float4 v, u64& hi64, u64& lo64) {
    u16 h0,l0,h1,l1,h2,l2,h3,l3;
    split_bf(v.x,h0,l0); split_bf(v.y,h1,l1);
    split_bf(v.z,h2,l2); split_bf(v.w,h3,l3);
    hi64 = (u64)h0 | ((u64)h1 << 16) | ((u64)h2 << 32) | ((u64)h3 << 48);
    lo64 = (u64)l0 | ((u64)l1 << 16) | ((u64)l2 << 32) | ((u64)l3 << 48);
}

// LDS-only barrier: orders LDS traffic across waves WITHOUT draining vmcnt.
// __syncthreads() would emit s_waitcnt vmcnt(0) -> every step would serially
// wait for sc1 publish-store ACKS from the MALL (~0.3-0.7us) plus all
// in-flight prefetch/poll loads. This is the T4 "never drain vmcnt in the
// main loop" idiom. sched_barrier stops hipcc migrating code across it.
__device__ __forceinline__ void lds_barrier() {
    asm volatile("s_waitcnt lgkmcnt(0)" ::: "memory");
    __builtin_amdgcn_s_barrier();
    __builtin_amdgcn_sched_barrier(0);
}

// grid = 256 blocks: blockIdx = cb*16 + g
//   g  (0..15): batch group, batches 4g..4g+3
//   cb (0..15): column block, cols 64cb..64cb+63
// block = 256 threads = 4 waves; wave w owns cols 64cb+16w .. +15
//
// h exchange: tagged u64 values (tag=step)<<48 | lo_bf16<<16 | hi_bf16,
// published with ONE relaxed agent (sc0 sc1) store -> tag+data visible
// atomically, so publishes are fire-and-forget (no drain, no fence).
// Consumers poll their own data words until the tag matches.
// Slot parity (t&1) double-buffers; a slot is only overwritten (tag t+2)
// after every peer published tag t+1, which is strictly after their tag-t
// reads of that slot completed -> race-free.
__global__ __launch_bounds__(256, 1) void leaky_rnn(
    const float* __restrict__ x, const float* __restrict__ eps,
    const float* __restrict__ in_w, const float* __restrict__ in_b,
    const float* __restrict__ W, const float* __restrict__ taus,
    float* __restrict__ out, u64* __restrict__ hbf, unsigned* __restrict__ cnt)
{
    __shared__ float Wl[128 * 68];           // init-only W staging
    __shared__ u16 xs_hi[2 * XS_HALF];       // double-buffered x tile
    __shared__ u16 xs_lo[2 * XS_HALF];
    __shared__ u16 hs_hi[4 * HS_STRIDE];
    __shared__ u16 hs_lo[4 * HS_STRIDE];

    const int tid  = threadIdx.x;
    const int wave = tid >> 6;
    const int lane = tid & 63;
    const int n    = lane & 15;
    const int quad = lane >> 4;
    const int g    = blockIdx.x & 15;
    const int cb   = blockIdx.x >> 4;
    const int jme  = cb * 64 + wave * 16 + n;   // my output column

    // ---- init: W column-slice -> split-bf16 register B-fragments ----
    // FULL unroll: runtime-indexed ext_vector arrays go to scratch (17 GB lesson).
    short8 whi[32], wlo[32];
    #pragma unroll
    for (int ph = 0; ph < 8; ++ph) {            // 8 phases x 128 rows
        #pragma unroll
        for (int ii = 0; ii < 8; ++ii) {        // stage 128x64 fp32 tile
            int f4i = ii * 256 + tid;           // 2048 float4
            int row = f4i >> 4, c4 = (f4i & 15) * 4;
            *(float4*)(Wl + row * 68 + c4) =
                *(const float4*)(W + (size_t)(ph * 128 + row) * H_ + cb * 64 + c4);
        }
        __syncthreads();
        #pragma unroll
        for (int ckl = 0; ckl < 4; ++ckl) {     // K-chunks of 32 within phase
            short8 fh, fl;
            #pragma unroll
            for (int i = 0; i < 8; ++i) {
                float v = Wl[(ckl * 32 + quad * 8 + i) * 68 + wave * 16 + n];
                u16 h, l; split_bf(v, h, l);
                fh[i] = (short)h; fl[i] = (short)l;
            }
            whi[ph * 4 + ckl] = fh;
            wlo[ph * 4 + ckl] = fl;
        }
        __syncthreads();
    }

    // in_w fragments: B[k][col] = in_w[col][k] -> 8 consecutive fp32 per chunk
    short8 iwhi[8], iwlo[8];
    #pragma unroll
    for (int ck = 0; ck < 8; ++ck) {
        float4 a = *(const float4*)(in_w + (size_t)jme * I_ + ck * 32 + quad * 8);
        float4 b = *(const float4*)(in_w + (size_t)jme * I_ + ck * 32 + quad * 8 + 4);
        short8 fh, fl;
        float vv[8] = {a.x, a.y, a.z, a.w, b.x, b.y, b.z, b.w};
        #pragma unroll
        for (int i = 0; i < 8; ++i) {
            u16 h, l; split_bf(vv[i], h, l);
            fh[i] = (short)h; fl[i] = (short)l;
        }
        iwhi[ck] = fh; iwlo[ck] = fl;
    }

    // per-column params (alpha time-invariant)
    float tv = taus[jme];
    float sg = 1.0f / (1.0f + __expf(-tv));
    float al = 10.0f / (sg * 90.0f + 10.0f);   // DT / (sigmoid(taus)*range + min)
    float om = 1.0f - al;
    float bj = in_b[jme];
    float hm[4] = {0.f, 0.f, 0.f, 0.f};        // fp32 master h (quad-0 lanes)

    const int bb = tid >> 6, cc = (tid & 63) * 4;   // my x-staging slot

    // ---- prologue: stage xs(0) into parity 0; prefetch x(1), eps(0) ----
    {
        float4 x0 = *(const float4*)(x + ((size_t)(g * 4 + bb) * T_ + 0) * I_ + cc);
        u64 hi64, lo64; split4(x0, hi64, lo64);
        *(u64*)(xs_hi + bb * XS_STRIDE + cc) = hi64;
        *(u64*)(xs_lo + bb * XS_STRIDE + cc) = lo64;
    }
    float4 xv = *(const float4*)(x + ((size_t)(g * 4 + bb) * T_ + 1) * I_ + cc);
    float epr[4] = {0.f, 0.f, 0.f, 0.f};
    if (quad == 0) {
        #pragma unroll
        for (int r = 0; r < 4; ++r)
            epr[r] = eps[((size_t)(g * 4 + r) * T_ + 0) * H_ + jme];
    }
    lds_barrier();                                   // xs(0) visible to all waves

    #pragma unroll 1
    for (int t = 0; t < T_; ++t) {
        const int p  = t & 1;
        const u32 tt = (u32)t;

        // ---- issue tagged h_t poll loads (16 u64/thread, one sweep) ----
        u64 hv[16];
        u64* src8 = hbf + ((size_t)p * 16 + g) * 4096;
        #pragma unroll
        for (int ii = 0; ii < 16; ++ii)
            hv[ii] = __hip_atomic_load(src8 + ii * 256 + tid,
                                       __ATOMIC_RELAXED, __HIP_MEMORY_SCOPE_AGENT);

        // ---- x @ in_w^T while the sweep is in flight (24 MFMAs) ----
        // acc rotation (3ck+j)&7: any 8 consecutive MFMAs hit distinct accs.
        floatx4 acc[8];
        #pragma unroll
        for (int a8 = 0; a8 < 8; ++a8) { floatx4 z = {0.f,0.f,0.f,0.f}; acc[a8] = z; }
        {
            const u16* xh = xs_hi + p * XS_HALF + (n & 3) * XS_STRIDE + quad * 8;
            const u16* xl = xs_lo + p * XS_HALF + (n & 3) * XS_STRIDE + quad * 8;
            #pragma unroll
            for (int ck = 0; ck < 8; ++ck) {
                short8 ah  = *(const short8*)(xh + ck * 32);
                short8 al8 = *(const short8*)(xl + ck * 32);
                acc[(3*ck+0)&7] = MFMA16(ah,  iwhi[ck], acc[(3*ck+0)&7], 0, 0, 0);
                acc[(3*ck+1)&7] = MFMA16(ah,  iwlo[ck], acc[(3*ck+1)&7], 0, 0, 0);
                acc[(3*ck+2)&7] = MFMA16(al8, iwhi[ck], acc[(3*ck+2)&7], 0, 0, 0);
            }
        }

        // ---- tag verify + re-poll (mild backoff after 2 failed sweeps) ----
        {
            u32 pend = 0;
            #pragma unroll
            for (int ii = 0; ii < 16; ++ii)
                if ((u32)(hv[ii] >> 48) != tt) pend |= (1u << ii);
            int tries = 0;
            while (pend) {
                if (++tries > 2) __builtin_amdgcn_s_sleep(1);
                #pragma unroll
                for (int ii = 0; ii < 16; ++ii)
                    if (pend & (1u << ii))
                        hv[ii] = __hip_atomic_load(src8 + ii * 256 + tid,
                                                   __ATOMIC_RELAXED, __HIP_MEMORY_SCOPE_AGENT);
                #pragma unroll
                for (int ii = 0; ii < 16; ++ii)
                    if ((u32)(hv[ii] >> 48) == tt) pend &= ~(1u << ii);
            }
        }

        // ---- unpack pre-split bf16 h -> LDS ----
        #pragma unroll
        for (int ii = 0; ii < 16; ++ii) {
            int idx = ii * 256 + tid;              // 4096 = [4][1024]
            int b = idx >> 10, c = idx & 1023;
            hs_hi[b * HS_STRIDE + c] = (u16)hv[ii];
            hs_lo[b * HS_STRIDE + c] = (u16)(hv[ii] >> 16);
        }
        lds_barrier();                                          // S2: hs ready

        // ---- prefetch x(t+2)/eps(t+1): long-latency, off-path ----
        float4 xvn;
        float eprn[4] = {0.f, 0.f, 0.f, 0.f};
        {
            int tn = (t < T_ - 2) ? t + 2 : T_ - 1;
            xvn = *(const float4*)(x + ((size_t)(g * 4 + bb) * T_ + tn) * I_ + cc);
            int te = (t < T_ - 1) ? t + 1 : t;
            if (quad == 0) {
                #pragma unroll
                for (int r = 0; r < 4; ++r)
                    eprn[r] = eps[((size_t)(g * 4 + r) * T_ + te) * H_ + jme];
            }
        }

        // ---- h @ W: 32 K-chunks x 3 split terms = 96 MFMAs ----
        {
            const u16* hh = hs_hi + (n & 3) * HS_STRIDE + quad * 8;
            const u16* hl = hs_lo + (n & 3) * HS_STRIDE + quad * 8;
            #pragma unroll
            for (int ck = 0; ck < 32; ++ck) {
                short8 ah  = *(const short8*)(hh + ck * 32);
                short8 al8 = *(const short8*)(hl + ck * 32);
                acc[(3*ck+0)&7] = MFMA16(ah,  whi[ck], acc[(3*ck+0)&7], 0, 0, 0);
                acc[(3*ck+1)&7] = MFMA16(ah,  wlo[ck], acc[(3*ck+1)&7], 0, 0, 0);
                acc[(3*ck+2)&7] = MFMA16(al8, whi[ck], acc[(3*ck+2)&7], 0, 0, 0);
            }
        }

        // ---- epilogue: publish FIRST (critical path), out stores after ----
        float hmn[4];
        if (quad == 0) {
            u64* dst8 = hbf + ((size_t)((t + 1) & 1) * 16 + g) * 4096;
            #pragma unroll
            for (int r = 0; r < 4; ++r) {
                float pre = acc[0][r] + acc[1][r] + acc[2][r] + acc[3][r]
                          + acc[4][r] + acc[5][r] + acc[6][r] + acc[7][r]
                          + bj + 0.1f * epr[r];
                float ex = __expf(2.0f * pre);                 // tanh = 1 - 2/(e^2x+1)
                float th = 1.0f - 2.0f / (ex + 1.0f);
                hmn[r] = om * hm[r] + al * th;
                u16 phh, pll; split_bf(hmn[r], phh, pll);
                u64 pk = (u64)phh | ((u64)pll << 16) | ((u64)(u32)(t + 1) << 48);
                // fire-and-forget: tag+data in one atomic 8B sc1 store
                __hip_atomic_store(dst8 + r * 1024 + jme, pk,
                                   __ATOMIC_RELAXED, __HIP_MEMORY_SCOPE_AGENT);
            }
            #pragma unroll
            for (int r = 0; r < 4; ++r) {
                hm[r] = hmn[r];
                out[((size_t)(g * 4 + r) * T_ + t) * H_ + jme] = hm[r];
            }
        }

        // ---- stage xs(t+1) into the other parity (xv holds x(t+1)) ----
        {
            u64 hi64, lo64; split4(xv, hi64, lo64);
            *(u64*)(xs_hi + (p ^ 1) * XS_HALF + bb * XS_STRIDE + cc) = hi64;
            *(u64*)(xs_lo + (p ^ 1) * XS_HALF + bb * XS_STRIDE + cc) = lo64;
        }

        // roll prefetched registers
        xv = xvn;
        #pragma unroll
        for (int r = 0; r < 4; ++r) epr[r] = eprn[r];

        lds_barrier();   // S9: xs(t+1) visible; hs(t) reads all consumed.
                         // No vmcnt drain: publish acks + prefetches float.
    }
}

extern "C" void kernel_launch(void* const* d_in, const int* in_sizes, int n_in,
                              void* d_out, int out_size, void* d_ws, size_t ws_size,
                              hipStream_t stream) {
    const float* x    = (const float*)d_in[0];
    const float* eps  = (const float*)d_in[1];
    const float* in_w = (const float*)d_in[2];
    const float* in_b = (const float*)d_in[3];
    const float* W    = (const float*)d_in[4];
    const float* taus = (const float*)d_in[5];
    float* out = (float*)d_out;

    unsigned* cnt = (unsigned*)d_ws;                   // unused (kept for layout)
    u64* hbf = (u64*)((char*)d_ws + 4096);             // [parity][16 groups][4096] u64

    // zero BOTH parity slots: tag 0 == step 0 (h0 = 0); stale tags from a
    // previous dispatch must never alias a live step tag.
    hipMemsetAsync(d_ws, 0, 4096 + 2 * 16 * 4096 * sizeof(u64), stream);

    leaky_rnn<<<dim3(256), dim3(256), 0, stream>>>(x, eps, in_w, in_b, W, taus,
                                                   out, hbf, cnt);
}